// Round 15
// baseline (202.484 us; speedup 1.0000x reference)
//
#include <hip/hip_runtime.h>
#include <cstdint>

typedef __attribute__((ext_vector_type(8))) short short8;
typedef __attribute__((ext_vector_type(16))) float f32x16;
typedef __attribute__((ext_vector_type(4))) unsigned int uint4v;

__device__ inline uint32_t f2bf(float f) {
    union { float f; uint32_t u; } x; x.f = f;
    return (x.u + 0x7FFF + ((x.u >> 16) & 1)) >> 16;
}
__device__ inline uint32_t fbits(float f) {
    union { float f; uint32_t u; } x; x.f = f;
    return x.u;
}
__device__ inline float bflo(uint32_t u) {
    union { uint32_t u; float f; } x; x.u = u << 16; return x.f;
}
__device__ inline float bfhi(uint32_t u) {
    union { uint32_t u; float f; } x; x.u = u & 0xFFFF0000u; return x.f;
}

// Pass 1: build X (bf16) in MFMA-fragment order; prep folded in.
// tid <-> 16-B piece: tid = ((img*1024 + site)*4 + kidx)*64 + l
__global__ __launch_bounds__(256) void k_xform(
    const float* __restrict__ wu, const float* __restrict__ wl,
    uint4v* __restrict__ X,
    const float* __restrict__ kk, uint16_t* __restrict__ ktb,
    const float* __restrict__ buI, const float* __restrict__ blI,
    float* __restrict__ buO, float* __restrict__ blO)
{
    int tid  = blockIdx.x * 256 + threadIdx.x;   // 16384 blocks -> 4Mi pieces

    if (tid < 36864 + 512) {                     // folded prep
        if (tid < 36864) ktb[tid] = (uint16_t)f2bf(kk[tid]);
        else if (tid < 36864 + 256) buO[tid - 36864] = buI[tid - 36864];
        else blO[tid - 36864 - 256] = blI[tid - 36864 - 256];
    }

    int l    = tid & 63;
    int kidx = (tid >> 6) & 3;
    int site = (tid >> 8) & 1023;
    int img  = tid >> 18;                        // b*2 + src
    int b    = img >> 1;
    const float* src = (img & 1) ? wl : wu;
    int o = l & 31, ch = l >> 5;

    const float* p = src + ((size_t)b * 65536 + (size_t)site * 64
                            + kidx * 16 + ch * 8) * 32 + o;
    uint4v w;
    #pragma unroll
    for (int pr = 0; pr < 4; pr++) {
        float g0 = p[(2 * pr) * 32];
        float g1 = p[(2 * pr + 1) * 32];
        w[pr] = __builtin_amdgcn_perm(fbits(g1), fbits(g0), 0x07060302u);
    }
    X[tid] = w;
}

// Pass 2: ONE PIXEL PER WAVE (both ci-halves). acc = 32 regs -> 4 waves/SIMD.
// Sites ww = w-1+si, kw = 2-si (always valid). Per row: batch all 12 dwordx4.
// 16384 one-wave blocks = (b=XCD, UL, w, h).
__global__ __launch_bounds__(64, 4) void k_conv(
    const uint16_t* __restrict__ X, const uint16_t* __restrict__ ktb,
    const float* __restrict__ bias,
    float* __restrict__ outU, float* __restrict__ outL,
    float* __restrict__ buO, float* __restrict__ blO)
{
    int l  = threadIdx.x;                   // one wave per block
    int o  = l & 31;
    int ch = l >> 5;

    int bid  = blockIdx.x;                  // 16384
    int b    = bid & 7;                     // XCD id
    int virt = bid >> 3;                    // 0..2047
    int h    = virt & 31;
    int w    = (virt >> 5) & 31;
    int UL   = virt >> 10;                  // 0/1
    int img  = b * 2 + UL;

    float* dst  = UL ? outL : outU;
    float* bdst = UL ? blO : buO;

    float bp = 0.f;
    f32x16 acc[2];                          // [c], 32 regs total
    acc[0] = (f32x16)0.f;
    acc[1] = (f32x16)0.f;

    bool sval[3] = { w != 0, true, w != 31 };
    const char* XB = (const char*)X;

    for (int r = 0; r < 3; r++) {
        int hh = h + 1 - r;
        if ((unsigned)hh >= 32u) continue;          // wave-uniform

        // ---- batch ALL 12 fragment loads for this row (3 sites x 4 kidx) ----
        uint4v bw[3][4];
        #pragma unroll
        for (int si = 0; si < 3; si++) {
            int ww  = w - 1 + si;
            int wwc = ((unsigned)ww < 32u) ? ww : 0;
            const char* ps = XB + ((size_t)(img * 1024 + hh * 32 + wwc)) * 4096
                                + (size_t)l * 16;
            if (sval[si]) {
                #pragma unroll
                for (int kidx = 0; kidx < 4; kidx++)
                    bw[si][kidx] = *(const uint4v*)(ps + kidx * 1024);
            } else {
                #pragma unroll
                for (int kidx = 0; kidx < 4; kidx++) bw[si][kidx] = (uint4v)0u;
            }
        }

        // ---- consume per kidx: 6 A-frags, bias (center site), 6 MFMA ----
        #pragma unroll
        for (int kidx = 0; kidx < 4; kidx++) {
            if (r == 1) {   // bias: this pixel's own X (site index 1), once per kidx
                float4 b0 = *(const float4*)(bias + kidx * 16 + ch * 8);
                float4 b1 = *(const float4*)(bias + kidx * 16 + ch * 8 + 4);
                float bb[8] = {b0.x, b0.y, b0.z, b0.w, b1.x, b1.y, b1.z, b1.w};
                #pragma unroll
                for (int pr = 0; pr < 4; pr++) {
                    bp = fmaf(bflo(bw[1][kidx][pr]), bb[2 * pr],
                         fmaf(bfhi(bw[1][kidx][pr]), bb[2 * pr + 1], bp));
                }
            }
            #pragma unroll
            for (int si = 0; si < 3; si++) {
                int kw = 2 - si;                    // always in [0,2]
                short8 Bf = __builtin_bit_cast(short8, bw[si][kidx]);
                #pragma unroll
                for (int c = 0; c < 2; c++) {
                    short8 A = *(const short8*)&ktb[(((r * 3 + kw) * 64) + c * 32 + (l & 31)) * 64
                                                    + kidx * 16 + ch * 8];
                    acc[c] = __builtin_amdgcn_mfma_f32_32x32x16_bf16(
                        A, Bf, acc[c], 0, 0, 0);
                }
            }
        }
    }

    // bias reduction: lanes l, l^32 share o
    bp += __shfl_xor(bp, 32);
    if (l < 32) atomicAdd(&bdst[b * 32 + o], bp);

    // stores: col = o (coalesced), row = (reg&3)+8*(reg>>2)+4*(lane>>5)
    #pragma unroll
    for (int c = 0; c < 2; c++) {
        float* base = dst + ((size_t)b * 65536 + (size_t)(h * 32 + w) * 64 + c * 32) * 32;
        #pragma unroll
        for (int reg = 0; reg < 16; reg++) {
            int row = (reg & 3) + 8 * (reg >> 2) + 4 * (l >> 5);
            base[row * 32 + o] = acc[c][reg];
        }
    }
}

extern "C" void kernel_launch(void* const* d_in, const int* in_sizes, int n_in,
                              void* d_out, int out_size, void* d_ws, size_t ws_size,
                              hipStream_t stream) {
    const float* wu   = (const float*)d_in[1];
    const float* buI  = (const float*)d_in[2];
    const float* wl   = (const float*)d_in[3];
    const float* blI  = (const float*)d_in[4];
    const float* kk   = (const float*)d_in[5];
    const float* bias = (const float*)d_in[6];

    float* out  = (float*)d_out;
    float* outU = out;
    float* buO  = out + 16777216;
    float* outL = out + 16777216 + 256;
    float* blO  = out + 2 * 16777216 + 256;

    uint16_t* ktb = (uint16_t*)d_ws;                       // 73728 B
    const size_t XOFF = 131072;                            // 128 KiB aligned
    uint4v* X = (uint4v*)((char*)d_ws + XOFF);             // 64 MiB

    k_xform<<<16384, 256, 0, stream>>>(wu, wl, X, kk, ktb, buI, blI, buO, blO);
    k_conv<<<16384, 64, 0, stream>>>((const uint16_t*)X, ktb, bias,
                                     outU, outL, buO, blO);
}

// Round 16
// 103.657 us; speedup vs baseline: 1.9534x; 1.9534x over previous
//
#include <hip/hip_runtime.h>
#include <cstdint>

typedef __attribute__((ext_vector_type(8))) short short8;
typedef __attribute__((ext_vector_type(16))) float f32x16;
typedef __attribute__((ext_vector_type(4))) unsigned int uint4v;

__device__ inline uint32_t f2bf(float f) {
    union { float f; uint32_t u; } x; x.f = f;
    return (x.u + 0x7FFF + ((x.u >> 16) & 1)) >> 16;
}
__device__ inline uint32_t fbits(float f) {
    union { float f; uint32_t u; } x; x.f = f;
    return x.u;
}
__device__ inline float bflo(uint32_t u) {
    union { uint32_t u; float f; } x; x.u = u << 16; return x.f;
}
__device__ inline float bfhi(uint32_t u) {
    union { uint32_t u; float f; } x; x.u = u & 0xFFFF0000u; return x.f;
}

// Pass 1: X (bf16, MFMA-fragment order) + prep (bias-out init, AF build).
// X piece: tid = ((img*1024 + site)*4 + kidx)*64 + l ; elem e = src[b][site][co][o],
//          co = kidx*16+(l>>5)*8+e, o = l&31.
// AF piece: fragment-order kernel table: AF[((tap*4+kidx)*2+c)*64 + l] holds the
//          8 bf16 A-elems ktb[(tap*64 + c*32 + (l&31))*64 + kidx*16 + (l>>5)*8 + e].
__global__ __launch_bounds__(256) void k_xform(
    const float* __restrict__ wu, const float* __restrict__ wl,
    uint4v* __restrict__ X,
    const float* __restrict__ kk, uint4v* __restrict__ AF,
    const float* __restrict__ buI, const float* __restrict__ blI,
    float* __restrict__ buO, float* __restrict__ blO)
{
    int tid = blockIdx.x * 256 + threadIdx.x;   // 16384 blocks -> 4Mi pieces

    if (tid < 512 + 4608) {                     // folded prep
        if (tid < 256) buO[tid] = buI[tid];
        else if (tid < 512) blO[tid - 256] = blI[tid - 256];
        else {
            int a    = tid - 512;               // 4608 AF pieces
            int al   = a & 63;
            int c    = (a >> 6) & 1;
            int kidx = (a >> 7) & 3;
            int tap  = a >> 9;                  // 0..8
            const float* kp = kk + ((size_t)tap * 64 + c * 32 + (al & 31)) * 64
                                 + kidx * 16 + (al >> 5) * 8;
            uint4v w;
            #pragma unroll
            for (int pr = 0; pr < 4; pr++)
                w[pr] = f2bf(kp[2 * pr]) | (f2bf(kp[2 * pr + 1]) << 16);   // RNE
            AF[((tap * 4 + kidx) * 2 + c) * 64 + al] = w;
        }
    }

    int l    = tid & 63;
    int kidx = (tid >> 6) & 3;
    int site = (tid >> 8) & 1023;
    int img  = tid >> 18;                       // b*2 + UL
    int b    = img >> 1;
    const float* src = (img & 1) ? wl : wu;
    int o = l & 31, ch = l >> 5;

    const float* p = src + ((size_t)b * 65536 + (size_t)site * 64
                            + kidx * 16 + ch * 8) * 32 + o;
    uint4v w;
    #pragma unroll
    for (int pr = 0; pr < 4; pr++) {
        float g0 = p[(2 * pr) * 32];
        float g1 = p[(2 * pr + 1) * 32];
        w[pr] = __builtin_amdgcn_perm(fbits(g1), fbits(g0), 0x07060302u);
    }
    X[tid] = w;
}

// Pass 2: wave = 2 pixels x 1 ci-half (acc 32 regs). Block = 256 thr = 4 waves
// (2 w-pairs x 2 ci-halves) sharing X rows; UL serialized (XCD X set = 1 img).
// All A/B loads are 1-KB-contiguous dwordx4. launch_bounds(256,3): 3 waves/SIMD.
__global__ __launch_bounds__(256, 3) void k_conv(
    const uint16_t* __restrict__ X, const uint16_t* __restrict__ AF,
    const float* __restrict__ bias,
    float* __restrict__ outU, float* __restrict__ outL,
    float* __restrict__ buO, float* __restrict__ blO)
{
    int tdx  = threadIdx.x;
    int l    = tdx & 63;
    int wid  = tdx >> 6;        // 0..3
    int o    = l & 31;
    int ch   = l >> 5;
    int c    = wid >> 1;        // ci-half owned by this wave
    int wsel = wid & 1;

    int bid = blockIdx.x;       // 2048
    int b   = bid & 7;          // XCD id
    int v   = bid >> 3;         // 0..255
    int h   = v & 31;
    int wq  = v >> 5;           // 0..7
    int w0  = wq * 4 + wsel * 2;   // wave's first pixel w

    bool sval[4] = { w0 != 0, true, true, w0 + 2 != 32 };
    const char* XB  = (const char*)X;
    const char* AFB = (const char*)AF;

    for (int UL = 0; UL < 2; UL++) {
        int img = b * 2 + UL;
        float* dst  = UL ? outL : outU;
        float* bdst = UL ? blO : buO;

        float bp = 0.f;
        f32x16 acc[2];              // [tw]
        acc[0] = (f32x16)0.f;
        acc[1] = (f32x16)0.f;

        for (int r = 0; r < 3; r++) {
            int hh = h + 1 - r;
            if ((unsigned)hh >= 32u) continue;      // wave-uniform

            // ---- batch ALL 16 B-fragment loads (4 sites x 4 kidx, 1KB each) ----
            uint4v bw[4][4];
            #pragma unroll
            for (int si = 0; si < 4; si++) {
                int ww  = w0 - 1 + si;
                int wwc = ((unsigned)ww < 32u) ? ww : 0;
                const char* ps = XB + ((size_t)(img * 1024 + hh * 32 + wwc)) * 4096
                                    + (size_t)l * 16;
                if (sval[si]) {
                    #pragma unroll
                    for (int kidx = 0; kidx < 4; kidx++)
                        bw[si][kidx] = *(const uint4v*)(ps + kidx * 1024);
                } else {
                    #pragma unroll
                    for (int kidx = 0; kidx < 4; kidx++) bw[si][kidx] = (uint4v)0u;
                }
            }

            // ---- consume per kidx: 3 A-frags (this c), bias, 6 MFMA ----
            #pragma unroll
            for (int kidx = 0; kidx < 4; kidx++) {
                short8 A[3];
                #pragma unroll
                for (int kw = 0; kw < 3; kw++)
                    A[kw] = *(const short8*)(AFB
                            + (size_t)((((r * 3 + kw) * 4 + kidx) * 2 + c) * 64 + l) * 16);

                if (r == 1 && c == 0) {     // bias: own pixels (sites 1,2), c0 wave only
                    float4 b0 = *(const float4*)(bias + kidx * 16 + ch * 8);
                    float4 b1 = *(const float4*)(bias + kidx * 16 + ch * 8 + 4);
                    float bb[8] = {b0.x, b0.y, b0.z, b0.w, b1.x, b1.y, b1.z, b1.w};
                    #pragma unroll
                    for (int pr = 0; pr < 4; pr++) {
                        bp = fmaf(bflo(bw[1][kidx][pr]), bb[2 * pr],
                             fmaf(bfhi(bw[1][kidx][pr]), bb[2 * pr + 1], bp));
                        bp = fmaf(bflo(bw[2][kidx][pr]), bb[2 * pr],
                             fmaf(bfhi(bw[2][kidx][pr]), bb[2 * pr + 1], bp));
                    }
                }

                #pragma unroll
                for (int si = 0; si < 4; si++) {
                    short8 Bf = __builtin_bit_cast(short8, bw[si][kidx]);
                    #pragma unroll
                    for (int tw = 0; tw < 2; tw++) {
                        int kw = tw + 2 - si;           // compile-time under unroll
                        if (kw >= 0 && kw <= 2)
                            acc[tw] = __builtin_amdgcn_mfma_f32_32x32x16_bf16(
                                A[kw], Bf, acc[tw], 0, 0, 0);
                    }
                }
            }
        }

        // bias reduction: lanes l, l^32 share o; one wave per pixel-pair (c==0)
        bp += __shfl_xor(bp, 32);
        if (l < 32 && c == 0) atomicAdd(&bdst[b * 32 + o], bp);

        // stores: col = o (coalesced), row = (reg&3)+8*(reg>>2)+4*(lane>>5)
        #pragma unroll
        for (int tw = 0; tw < 2; tw++) {
            int w = w0 + tw;
            float* base = dst + ((size_t)b * 65536 + (size_t)(h * 32 + w) * 64 + c * 32) * 32;
            #pragma unroll
            for (int reg = 0; reg < 16; reg++) {
                int row = (reg & 3) + 8 * (reg >> 2) + 4 * (l >> 5);
                base[row * 32 + o] = acc[tw][reg];
            }
        }
    }
}

extern "C" void kernel_launch(void* const* d_in, const int* in_sizes, int n_in,
                              void* d_out, int out_size, void* d_ws, size_t ws_size,
                              hipStream_t stream) {
    const float* wu   = (const float*)d_in[1];
    const float* buI  = (const float*)d_in[2];
    const float* wl   = (const float*)d_in[3];
    const float* blI  = (const float*)d_in[4];
    const float* kk   = (const float*)d_in[5];
    const float* bias = (const float*)d_in[6];

    float* out  = (float*)d_out;
    float* outU = out;
    float* buO  = out + 16777216;
    float* outL = out + 16777216 + 256;
    float* blO  = out + 2 * 16777216 + 256;

    uint4v* AF = (uint4v*)d_ws;                            // 73728 B
    const size_t XOFF = 131072;                            // 128 KiB aligned
    uint4v* X = (uint4v*)((char*)d_ws + XOFF);             // 64 MiB

    k_xform<<<16384, 256, 0, stream>>>(wu, wl, X, kk, AF, buI, blI, buO, blO);
    k_conv<<<2048, 256, 0, stream>>>((const uint16_t*)X, (const uint16_t*)AF, bias,
                                     outU, outL, buO, blO);
}